// Round 7
// baseline (445.228 us; speedup 1.0000x reference)
//
#include <hip/hip_runtime.h>

#define N_NODES  50000
#define N_EDGES  800000
#define N_GRAPHS 128
#define DIM      128
#define K2       256
#define CLS      10
#define NB_SCAN  ((N_NODES + 255) / 256)   // 196
#define NPART    8                          // dst partitions == XCD count
#define PSIZE    (N_NODES / NPART)          // 6250
#define NCHUNK   64
#define CHUNK    (N_EDGES / NCHUNK)         // 12500
#define PCAP     131072                     // staging capacity per partition (mean 100K, sd ~300)

typedef __attribute__((ext_vector_type(8))) short bf16x8;
typedef __attribute__((ext_vector_type(4))) float f32x4;

__device__ inline unsigned short f2bf(float f) {
    unsigned u = __float_as_uint(f);
    unsigned r = (u + 0x7FFFu + ((u >> 16) & 1u)) >> 16;   // RNE
    return (unsigned short)r;
}
__device__ inline float bf2f(unsigned short s) {
    return __uint_as_float(((unsigned)s) << 16);
}

// ---------------- phase A: bin edges by dst partition into contiguous staging ----------------
__global__ __launch_bounds__(256) void k_bin(const int* __restrict__ src, const int* __restrict__ dst,
                                             int2* __restrict__ stag, int* __restrict__ gcount) {
    __shared__ int lcount[NPART];
    __shared__ int lbase[NPART];
    __shared__ int lcur[NPART];
    const int tid = threadIdx.x;
    const int lo = blockIdx.x * CHUNK;
    if (tid < NPART) lcount[tid] = 0;
    __syncthreads();
    // sweep 1: histogram
    for (int i = lo + tid; i < lo + CHUNK; i += 256) {
        int p = dst[i] / PSIZE;
        atomicAdd(&lcount[p], 1);
    }
    __syncthreads();
    if (tid < NPART) {
        lbase[tid] = atomicAdd(&gcount[tid], lcount[tid]);
        lcur[tid] = 0;
    }
    __syncthreads();
    // sweep 2 (chunk L2-hot): place
    for (int i = lo + tid; i < lo + CHUNK; i += 256) {
        int d = dst[i];
        int p = d / PSIZE;
        int slot = atomicAdd(&lcur[p], 1);
        stag[(size_t)p * PCAP + lbase[p] + slot] = make_int2(src[i], d);
    }
}

// ---------------- phase B: degree count from staged pairs (XCD-local) ----------------
__global__ __launch_bounds__(256) void k_deg2(const int2* __restrict__ stag, const int* __restrict__ gcount,
                                              int* __restrict__ deg) {
    const int part = blockIdx.x & (NPART - 1);
    const int blk = blockIdx.x >> 3;            // 0..63
    const int n = gcount[part];
    const int2* s = stag + (size_t)part * PCAP;
    for (int i = blk * 256 + threadIdx.x; i < n; i += 64 * 256)
        atomicAdd(&deg[s[i].y], 1);
}

// ---------------- phase D: CSR fill from staged pairs (XCD-local) ----------------
__global__ __launch_bounds__(256) void k_fill2(const int2* __restrict__ stag, const int* __restrict__ gcount,
                                               int* __restrict__ cursor, int* __restrict__ eidx) {
    const int part = blockIdx.x & (NPART - 1);
    const int blk = blockIdx.x >> 3;
    const int n = gcount[part];
    const int2* s = stag + (size_t)part * PCAP;
    for (int i = blk * 256 + threadIdx.x; i < n; i += 64 * 256) {
        int2 e = s[i];
        int pos = atomicAdd(&cursor[e.y], 1);
        eidx[pos] = e.x;
    }
}

// ---------------- graph counts via binary search (graph_ids sorted) ----------------
__global__ __launch_bounds__(128) void k_count_sorted(const int* __restrict__ gid, float* __restrict__ counts) {
    int g = threadIdx.x;
    int lo = 0, hi = N_NODES;
    while (lo < hi) { int mid = (lo + hi) >> 1; if (gid[mid] < g) lo = mid + 1; else hi = mid; }
    int start = lo;
    lo = 0; hi = N_NODES;
    while (lo < hi) { int mid = (lo + hi) >> 1; if (gid[mid] <= g) lo = mid + 1; else hi = mid; }
    counts[g] = (float)(lo - start);
}

// ---------------- parallel 3-phase scan ----------------
__global__ __launch_bounds__(256) void k_scan_part(const int* __restrict__ deg,
                                                   int* __restrict__ rowptr, int* __restrict__ bsum) {
    __shared__ int s[256];
    const int tid = threadIdx.x;
    const int i = blockIdx.x * 256 + tid;
    int v = (i < N_NODES) ? deg[i] : 0;
    s[tid] = v;
    __syncthreads();
    for (int off = 1; off < 256; off <<= 1) {
        int add = (tid >= off) ? s[tid - off] : 0;
        __syncthreads();
        s[tid] += add;
        __syncthreads();
    }
    if (i < N_NODES) rowptr[i] = s[tid] - v;
    if (tid == 255) bsum[blockIdx.x] = s[255];
}

__global__ __launch_bounds__(256) void k_scan_top(const int* __restrict__ bsum, int* __restrict__ boff,
                                                  int* __restrict__ rowptr) {
    __shared__ int s[256];
    const int tid = threadIdx.x;
    int v = (tid < NB_SCAN) ? bsum[tid] : 0;
    s[tid] = v;
    __syncthreads();
    for (int off = 1; off < 256; off <<= 1) {
        int add = (tid >= off) ? s[tid - off] : 0;
        __syncthreads();
        s[tid] += add;
        __syncthreads();
    }
    if (tid < NB_SCAN) boff[tid] = s[tid] - v;
    if (tid == 0) rowptr[N_NODES] = N_EDGES;
}

__global__ __launch_bounds__(256) void k_scan_add(int* __restrict__ rowptr, const int* __restrict__ boff,
                                                  int* __restrict__ cursor) {
    const int i = blockIdx.x * 256 + threadIdx.x;
    if (i < N_NODES) {
        int r = rowptr[i] + boff[blockIdx.x];
        rowptr[i] = r;
        cursor[i] = r;
    }
}

// ---------------- features fp32 -> bf16 hcat0 h-part ----------------
__global__ __launch_bounds__(256) void k_cast(const float* __restrict__ f, unsigned short* __restrict__ c0) {
    int t = blockIdx.x * 256 + threadIdx.x;   // one per 8 elems
    if (t >= N_NODES * 16) return;
    int row = t >> 4, c8 = (t & 15) * 8;
    const float* p = f + (size_t)row * DIM + c8;
    float4 a = *(const float4*)p;
    float4 b = *(const float4*)(p + 4);
    uint4 v;
    v.x = f2bf(a.x) | ((unsigned)f2bf(a.y) << 16);
    v.y = f2bf(a.z) | ((unsigned)f2bf(a.w) << 16);
    v.z = f2bf(b.x) | ((unsigned)f2bf(b.y) << 16);
    v.w = f2bf(b.z) | ((unsigned)f2bf(b.w) << 16);
    *(uint4*)(c0 + (size_t)row * K2 + c8) = v;
}

// ---------------- weights: transpose + concat + hi/lo split ----------------
__global__ __launch_bounds__(256) void k_prep_w(const float* __restrict__ Ws0, const float* __restrict__ Wn0,
                                                const float* __restrict__ Ws1, const float* __restrict__ Wn1,
                                                const float* __restrict__ Ws2, const float* __restrict__ Wn2,
                                                unsigned short* __restrict__ hi, unsigned short* __restrict__ lo) {
    int t = blockIdx.x * 256 + threadIdx.x;
    if (t >= 3 * DIM * K2) return;
    int l = t / (DIM * K2), r = t % (DIM * K2);
    int n = r / K2, k = r % K2;
    const float* Ws = (l == 0) ? Ws0 : (l == 1) ? Ws1 : Ws2;
    const float* Wn = (l == 0) ? Wn0 : (l == 1) ? Wn1 : Wn2;
    float w = (k < DIM) ? Ws[k * DIM + n] : Wn[(k - DIM) * DIM + n];
    unsigned short h = f2bf(w);
    hi[t] = h;
    lo[t] = f2bf(w - bf2f(h));
}

// ---------------- gather: one wave per node, bf16 rows, fp32 accum ----------------
__global__ __launch_bounds__(256) void k_gather(const unsigned short* __restrict__ h,
                                                const int* __restrict__ rowptr,
                                                const int* __restrict__ eidx,
                                                unsigned short* __restrict__ msg) {
    const int node = (blockIdx.x * 256 + threadIdx.x) >> 6;
    const int lane = threadIdx.x & 63;
    if (node >= N_NODES) return;
    const int epar = lane >> 4;        // 4 edges in flight
    const int d0 = (lane & 15) * 8;    // 8 bf16 per lane = 16 B
    const int beg = rowptr[node], end = rowptr[node + 1];
    float acc[8] = {0.f, 0.f, 0.f, 0.f, 0.f, 0.f, 0.f, 0.f};
    for (int j = beg + epar; j < end; j += 4) {
        int s = eidx[j];
        uint4 v = *(const uint4*)(h + (size_t)s * K2 + d0);
        unsigned u[4] = {v.x, v.y, v.z, v.w};
#pragma unroll
        for (int i = 0; i < 4; ++i) {
            acc[2 * i]     += __uint_as_float(u[i] << 16);
            acc[2 * i + 1] += __uint_as_float(u[i] & 0xFFFF0000u);
        }
    }
#pragma unroll
    for (int i = 0; i < 8; ++i) {
        acc[i] += __shfl_xor(acc[i], 16);
        acc[i] += __shfl_xor(acc[i], 32);
    }
    if (epar == 0) {
        float inv = (end > beg) ? 1.0f / (float)(end - beg) : 0.f;
        unsigned short o[8];
#pragma unroll
        for (int i = 0; i < 8; ++i) o[i] = f2bf(acc[i] * inv);
        uint4 v;
        v.x = o[0] | ((unsigned)o[1] << 16);
        v.y = o[2] | ((unsigned)o[3] << 16);
        v.z = o[4] | ((unsigned)o[5] << 16);
        v.w = o[6] | ((unsigned)o[7] << 16);
        *(uint4*)(msg + (size_t)node * K2 + DIM + d0) = v;
    }
}

// ---------------- SAGE layer: bf16 MFMA, single K=256 GEMM ----------------
__global__ __launch_bounds__(256) void k_sage(const unsigned short* __restrict__ hin,  // [m][256]
                                              const unsigned short* __restrict__ whi,  // [n][256]
                                              const unsigned short* __restrict__ wlo,
                                              const float* __restrict__ bias,
                                              unsigned short* __restrict__ hout) {
    __shared__ unsigned short Ah[128 * 40];   // stride 40 shorts (80 B): 2-way bank alias = free
    __shared__ unsigned short Bh[128 * 40];
    __shared__ unsigned short Bl[128 * 40];
    const int tid = threadIdx.x;
    const int wv = tid >> 6, lane = tid & 63;
    const int m0 = blockIdx.x * 128;
    const int m_off = (wv >> 1) * 64, n_off = (wv & 1) * 64;
    const int l15 = lane & 15, q = lane >> 4;

    f32x4 acc[4][4];
#pragma unroll
    for (int a = 0; a < 4; ++a)
#pragma unroll
        for (int b = 0; b < 4; ++b) acc[a][b] = (f32x4){0.f, 0.f, 0.f, 0.f};

#pragma unroll 1
    for (int kt = 0; kt < 8; ++kt) {
        const int k0 = kt * 32;
#pragma unroll
        for (int i = 0; i < 2; ++i) {
            int idx = tid + i * 256;
            int row = idx >> 2, kq = (idx & 3) * 8;
            int gm = m0 + row;
            uint4 va = make_uint4(0u, 0u, 0u, 0u);
            if (gm < N_NODES) va = *(const uint4*)(hin + (size_t)gm * K2 + k0 + kq);
            *(uint4*)&Ah[row * 40 + kq] = va;
            *(uint4*)&Bh[row * 40 + kq] = *(const uint4*)(whi + (size_t)row * K2 + k0 + kq);
            *(uint4*)&Bl[row * 40 + kq] = *(const uint4*)(wlo + (size_t)row * K2 + k0 + kq);
        }
        __syncthreads();
        bf16x8 hf[4], wh[4], wl[4];
#pragma unroll
        for (int mt = 0; mt < 4; ++mt)
            hf[mt] = *(const bf16x8*)&Ah[(m_off + mt * 16 + l15) * 40 + q * 8];
#pragma unroll
        for (int nt = 0; nt < 4; ++nt) {
            wh[nt] = *(const bf16x8*)&Bh[(n_off + nt * 16 + l15) * 40 + q * 8];
            wl[nt] = *(const bf16x8*)&Bl[(n_off + nt * 16 + l15) * 40 + q * 8];
        }
#pragma unroll
        for (int mt = 0; mt < 4; ++mt)
#pragma unroll
            for (int nt = 0; nt < 4; ++nt) {
                acc[mt][nt] = __builtin_amdgcn_mfma_f32_16x16x32_bf16(wh[nt], hf[mt], acc[mt][nt], 0, 0, 0);
                acc[mt][nt] = __builtin_amdgcn_mfma_f32_16x16x32_bf16(wl[nt], hf[mt], acc[mt][nt], 0, 0, 0);
            }
        __syncthreads();
    }
#pragma unroll
    for (int nt = 0; nt < 4; ++nt) {
        int n = n_off + nt * 16 + q * 4;
        float4 bv = *(const float4*)(bias + n);
#pragma unroll
        for (int mt = 0; mt < 4; ++mt) {
            int m = m0 + m_off + mt * 16 + l15;
            if (m < N_NODES) {
                f32x4 a = acc[mt][nt];
                unsigned short o0 = f2bf(fmaxf(a[0] + bv.x, 0.f));
                unsigned short o1 = f2bf(fmaxf(a[1] + bv.y, 0.f));
                unsigned short o2 = f2bf(fmaxf(a[2] + bv.z, 0.f));
                unsigned short o3 = f2bf(fmaxf(a[3] + bv.w, 0.f));
                uint2 v;
                v.x = o0 | ((unsigned)o1 << 16);
                v.y = o2 | ((unsigned)o3 << 16);
                *(uint2*)(hout + (size_t)m * K2 + n) = v;
            }
        }
    }
}

// ---------------- graph mean-pool (bf16 h, sorted gids) ----------------
__global__ __launch_bounds__(256) void k_pool(const unsigned short* __restrict__ h,
                                              const int* __restrict__ gid,
                                              float* __restrict__ pooled) {
    int d = threadIdx.x & 127;
    int half = threadIdx.x >> 7;
    int n0 = blockIdx.x * 128;
    float acc = 0.f;
    int cur = -1;
    for (int i = half; i < 128; i += 2) {
        int n = n0 + i;
        if (n >= N_NODES) break;
        int g = gid[n];
        if (g != cur) {
            if (cur >= 0) atomicAdd(&pooled[(size_t)cur * DIM + d], acc);
            acc = 0.f;
            cur = g;
        }
        acc += bf2f(h[(size_t)n * K2 + d]);
    }
    if (cur >= 0) atomicAdd(&pooled[(size_t)cur * DIM + d], acc);
}

// ---------------- classifier (fp32) ----------------
__global__ __launch_bounds__(256) void k_final(const float* __restrict__ pooled,
                                               const float* __restrict__ counts,
                                               const float* __restrict__ Wf,
                                               const float* __restrict__ bf,
                                               float* __restrict__ out) {
    int t = blockIdx.x * 256 + threadIdx.x;
    if (t >= N_GRAPHS * CLS) return;
    int g = t / CLS, c = t % CLS;
    float inv = 1.0f / fmaxf(counts[g], 1.0f);
    float s = 0.f;
    for (int k = 0; k < DIM; ++k) s += pooled[(size_t)g * DIM + k] * Wf[k * CLS + c];
    out[t] = s * inv + bf[c];
}

extern "C" void kernel_launch(void* const* d_in, const int* in_sizes, int n_in,
                              void* d_out, int out_size, void* d_ws, size_t ws_size,
                              hipStream_t stream) {
    const float* features = (const float*)d_in[0];
    const int*   esrc     = (const int*)d_in[1];
    const int*   edst     = (const int*)d_in[2];
    const int*   gids     = (const int*)d_in[3];
    const float* bs[3]  = {(const float*)d_in[6], (const float*)d_in[9], (const float*)d_in[12]};
    const float* Wf = (const float*)d_in[13];
    const float* bfv = (const float*)d_in[14];
    float* out = (float*)d_out;

    // ---- workspace layout ----
    int* deg_i  = (int*)d_ws;            // 50000 used; +gcount in same memset block
    int* gcount = deg_i + 50000;         // 8   (covered by deg memset)
    int* rowptr = deg_i + 50048;         // 50064
    int* cursor = rowptr + 50064;        // 50048
    int* bsum   = cursor + 50048;        // 256
    int* boff   = bsum + 256;            // 256
    int* eidx   = boff + 256;            // 800000
    int2* stag  = (int2*)(eidx + 800000);        // 8*131072 int2 = 8 MB
    float* pooled = (float*)(stag + (size_t)NPART * PCAP);   // 16384
    float* counts = pooled + N_GRAPHS * DIM;     // 128
    unsigned short* C0  = (unsigned short*)(counts + 128);   // 50000*256 bf16
    unsigned short* C1  = C0 + (size_t)N_NODES * K2;
    unsigned short* C2  = C1 + (size_t)N_NODES * K2;
    unsigned short* Whi = C2 + (size_t)N_NODES * K2;         // 3*128*256
    unsigned short* Wlo = Whi + 3 * DIM * K2;
    // total ~89 MB

    hipMemsetAsync(deg_i, 0, 50048 * sizeof(int), stream);
    hipMemsetAsync(pooled, 0, N_GRAPHS * DIM * sizeof(float), stream);

    // CSR build: bin -> deg -> scan -> fill
    k_bin<<<NCHUNK, 256, 0, stream>>>(esrc, edst, stag, gcount);
    k_count_sorted<<<1, 128, 0, stream>>>(gids, counts);
    k_deg2<<<NPART * 64, 256, 0, stream>>>(stag, gcount, deg_i);
    k_scan_part<<<NB_SCAN, 256, 0, stream>>>(deg_i, rowptr, bsum);
    k_scan_top<<<1, 256, 0, stream>>>(bsum, boff, rowptr);
    k_scan_add<<<NB_SCAN, 256, 0, stream>>>(rowptr, boff, cursor);
    k_fill2<<<NPART * 64, 256, 0, stream>>>(stag, gcount, cursor, eidx);
    k_cast<<<(N_NODES * 16 + 255) / 256, 256, 0, stream>>>(features, C0);
    k_prep_w<<<(3 * DIM * K2 + 255) / 256, 256, 0, stream>>>(
        (const float*)d_in[4], (const float*)d_in[5],
        (const float*)d_in[7], (const float*)d_in[8],
        (const float*)d_in[10], (const float*)d_in[11], Whi, Wlo);

    unsigned short* C[4] = {C0, C1, C2, C0};
    for (int l = 0; l < 3; ++l) {
        k_gather<<<(N_NODES * 64 + 255) / 256, 256, 0, stream>>>(C[l], rowptr, eidx, C[l]);
        k_sage<<<(N_NODES + 127) / 128, 256, 0, stream>>>(
            C[l], Whi + (size_t)l * DIM * K2, Wlo + (size_t)l * DIM * K2, bs[l], C[l + 1]);
    }

    k_pool<<<(N_NODES + 127) / 128, 256, 0, stream>>>(C0, gids, pooled);
    k_final<<<(N_GRAPHS * CLS + 255) / 256, 256, 0, stream>>>(pooled, counts, Wf, bfv, out);
}

// Round 8
// 434.002 us; speedup vs baseline: 1.0259x; 1.0259x over previous
//
#include <hip/hip_runtime.h>

#define N_NODES  50000
#define N_EDGES  800000
#define N_GRAPHS 128
#define DIM      128
#define K2       256
#define CLS      10
#define NB_SCAN  ((N_NODES + 255) / 256)   // 196
#define NPART    8                          // dst partitions == XCD count
#define PSIZE    (N_NODES / NPART)          // 6250
#define NBIN     400
#define CHUNK    (N_EDGES / NBIN)           // 2000
#define PCAP     131072                     // staging capacity per partition

typedef __attribute__((ext_vector_type(8))) short bf16x8;
typedef __attribute__((ext_vector_type(4))) float f32x4;

__device__ inline unsigned short f2bf(float f) {
    unsigned u = __float_as_uint(f);
    unsigned r = (u + 0x7FFFu + ((u >> 16) & 1u)) >> 16;   // RNE
    return (unsigned short)r;
}
__device__ inline float bf2f(unsigned short s) {
    return __uint_as_float(((unsigned)s) << 16);
}

// ---------------- phase A: bin edges by dst partition (wave-aggregated LDS atomics) ----------------
__global__ __launch_bounds__(256) void k_bin(const int* __restrict__ src, const int* __restrict__ dst,
                                             int2* __restrict__ stag, int* __restrict__ gcount) {
    __shared__ int lcount[NPART];
    __shared__ int lbase[NPART];
    const int tid = threadIdx.x;
    const int lane = tid & 63;
    const int lo = blockIdx.x * CHUNK;
    if (tid < NPART) lcount[tid] = 0;
    __syncthreads();
    // sweep 1: wave-aggregated histogram
    for (int i = lo + tid; i < lo + CHUNK; i += 256) {
        int p = dst[i] / PSIZE;
#pragma unroll
        for (int q = 0; q < NPART; ++q) {
            unsigned long long m = __ballot(p == q);
            if (p == q) {
                int leader = __ffsll((long long)m) - 1;
                if (lane == leader) atomicAdd(&lcount[q], (int)__popcll(m));
            }
        }
    }
    __syncthreads();
    if (tid < NPART) {
        lbase[tid] = atomicAdd(&gcount[tid], lcount[tid]);
        lcount[tid] = 0;   // reuse as cursor
    }
    __syncthreads();
    // sweep 2 (L2-hot): wave-aggregated placement
    for (int i = lo + tid; i < lo + CHUNK; i += 256) {
        int d = dst[i];
        int p = d / PSIZE;
        int slot = 0;
#pragma unroll
        for (int q = 0; q < NPART; ++q) {
            unsigned long long m = __ballot(p == q);
            if (p == q) {
                int leader = __ffsll((long long)m) - 1;
                int rank = (int)__popcll(m & ((1ull << lane) - 1ull));
                int base;
                if (lane == leader) base = atomicAdd(&lcount[q], (int)__popcll(m));
                base = __shfl(base, leader);
                slot = base + rank;
            }
        }
        stag[(size_t)p * PCAP + lbase[p] + slot] = make_int2(src[i], d);
    }
}

// ---------------- phase B: degree count from staged pairs (XCD-local) ----------------
__global__ __launch_bounds__(256) void k_deg2(const int2* __restrict__ stag, const int* __restrict__ gcount,
                                              int* __restrict__ deg) {
    const int part = blockIdx.x & (NPART - 1);
    const int blk = blockIdx.x >> 3;            // 0..63
    const int n = gcount[part];
    const int2* s = stag + (size_t)part * PCAP;
    for (int i = blk * 256 + threadIdx.x; i < n; i += 64 * 256)
        atomicAdd(&deg[s[i].y], 1);
}

// ---------------- phase D: CSR fill from staged pairs (XCD-local) ----------------
__global__ __launch_bounds__(256) void k_fill2(const int2* __restrict__ stag, const int* __restrict__ gcount,
                                               int* __restrict__ cursor, int* __restrict__ eidx) {
    const int part = blockIdx.x & (NPART - 1);
    const int blk = blockIdx.x >> 3;
    const int n = gcount[part];
    const int2* s = stag + (size_t)part * PCAP;
    for (int i = blk * 256 + threadIdx.x; i < n; i += 64 * 256) {
        int2 e = s[i];
        int pos = atomicAdd(&cursor[e.y], 1);
        eidx[pos] = e.x;
    }
}

// ---------------- parallel 3-phase scan ----------------
__global__ __launch_bounds__(256) void k_scan_part(const int* __restrict__ deg,
                                                   int* __restrict__ rowptr, int* __restrict__ bsum) {
    __shared__ int s[256];
    const int tid = threadIdx.x;
    const int i = blockIdx.x * 256 + tid;
    int v = (i < N_NODES) ? deg[i] : 0;
    s[tid] = v;
    __syncthreads();
    for (int off = 1; off < 256; off <<= 1) {
        int add = (tid >= off) ? s[tid - off] : 0;
        __syncthreads();
        s[tid] += add;
        __syncthreads();
    }
    if (i < N_NODES) rowptr[i] = s[tid] - v;
    if (tid == 255) bsum[blockIdx.x] = s[255];
}

// top-level scan + graph counts (merged; both single-block jobs)
__global__ __launch_bounds__(256) void k_scan_top(const int* __restrict__ bsum, int* __restrict__ boff,
                                                  int* __restrict__ rowptr,
                                                  const int* __restrict__ gid, float* __restrict__ counts) {
    __shared__ int s[256];
    const int tid = threadIdx.x;
    // graph counts via binary search (graph_ids sorted)
    if (tid < N_GRAPHS) {
        int g = tid;
        int lo = 0, hi = N_NODES;
        while (lo < hi) { int mid = (lo + hi) >> 1; if (gid[mid] < g) lo = mid + 1; else hi = mid; }
        int start = lo;
        lo = 0; hi = N_NODES;
        while (lo < hi) { int mid = (lo + hi) >> 1; if (gid[mid] <= g) lo = mid + 1; else hi = mid; }
        counts[g] = (float)(lo - start);
    }
    int v = (tid < NB_SCAN) ? bsum[tid] : 0;
    s[tid] = v;
    __syncthreads();
    for (int off = 1; off < 256; off <<= 1) {
        int add = (tid >= off) ? s[tid - off] : 0;
        __syncthreads();
        s[tid] += add;
        __syncthreads();
    }
    if (tid < NB_SCAN) boff[tid] = s[tid] - v;
    if (tid == 0) rowptr[N_NODES] = N_EDGES;
}

__global__ __launch_bounds__(256) void k_scan_add(int* __restrict__ rowptr, const int* __restrict__ boff,
                                                  int* __restrict__ cursor) {
    const int i = blockIdx.x * 256 + threadIdx.x;
    if (i < N_NODES) {
        int r = rowptr[i] + boff[blockIdx.x];
        rowptr[i] = r;
        cursor[i] = r;
    }
}

// ---------------- features fp32 -> bf16 hcat0 h-part ----------------
__global__ __launch_bounds__(256) void k_cast(const float* __restrict__ f, unsigned short* __restrict__ c0) {
    int t = blockIdx.x * 256 + threadIdx.x;   // one per 8 elems
    if (t >= N_NODES * 16) return;
    int row = t >> 4, c8 = (t & 15) * 8;
    const float* p = f + (size_t)row * DIM + c8;
    float4 a = *(const float4*)p;
    float4 b = *(const float4*)(p + 4);
    uint4 v;
    v.x = f2bf(a.x) | ((unsigned)f2bf(a.y) << 16);
    v.y = f2bf(a.z) | ((unsigned)f2bf(a.w) << 16);
    v.z = f2bf(b.x) | ((unsigned)f2bf(b.y) << 16);
    v.w = f2bf(b.z) | ((unsigned)f2bf(b.w) << 16);
    *(uint4*)(c0 + (size_t)row * K2 + c8) = v;
}

// ---------------- weights: transpose + concat + hi/lo split ----------------
__global__ __launch_bounds__(256) void k_prep_w(const float* __restrict__ Ws0, const float* __restrict__ Wn0,
                                                const float* __restrict__ Ws1, const float* __restrict__ Wn1,
                                                const float* __restrict__ Ws2, const float* __restrict__ Wn2,
                                                unsigned short* __restrict__ hi, unsigned short* __restrict__ lo) {
    int t = blockIdx.x * 256 + threadIdx.x;
    if (t >= 3 * DIM * K2) return;
    int l = t / (DIM * K2), r = t % (DIM * K2);
    int n = r / K2, k = r % K2;
    const float* Ws = (l == 0) ? Ws0 : (l == 1) ? Ws1 : Ws2;
    const float* Wn = (l == 0) ? Wn0 : (l == 1) ? Wn1 : Wn2;
    float w = (k < DIM) ? Ws[k * DIM + n] : Wn[(k - DIM) * DIM + n];
    unsigned short h = f2bf(w);
    hi[t] = h;
    lo[t] = f2bf(w - bf2f(h));
}

// ---------------- gather: one wave per node, bf16 rows, fp32 accum ----------------
__global__ __launch_bounds__(256) void k_gather(const unsigned short* __restrict__ h,
                                                const int* __restrict__ rowptr,
                                                const int* __restrict__ eidx,
                                                unsigned short* __restrict__ msg) {
    const int node = (blockIdx.x * 256 + threadIdx.x) >> 6;
    const int lane = threadIdx.x & 63;
    if (node >= N_NODES) return;
    const int epar = lane >> 4;        // 4 edges in flight
    const int d0 = (lane & 15) * 8;    // 8 bf16 per lane = 16 B
    const int beg = rowptr[node], end = rowptr[node + 1];
    float acc[8] = {0.f, 0.f, 0.f, 0.f, 0.f, 0.f, 0.f, 0.f};
    for (int j = beg + epar; j < end; j += 4) {
        int s = eidx[j];
        uint4 v = *(const uint4*)(h + (size_t)s * K2 + d0);
        unsigned u[4] = {v.x, v.y, v.z, v.w};
#pragma unroll
        for (int i = 0; i < 4; ++i) {
            acc[2 * i]     += __uint_as_float(u[i] << 16);
            acc[2 * i + 1] += __uint_as_float(u[i] & 0xFFFF0000u);
        }
    }
#pragma unroll
    for (int i = 0; i < 8; ++i) {
        acc[i] += __shfl_xor(acc[i], 16);
        acc[i] += __shfl_xor(acc[i], 32);
    }
    if (epar == 0) {
        float inv = (end > beg) ? 1.0f / (float)(end - beg) : 0.f;
        unsigned short o[8];
#pragma unroll
        for (int i = 0; i < 8; ++i) o[i] = f2bf(acc[i] * inv);
        uint4 v;
        v.x = o[0] | ((unsigned)o[1] << 16);
        v.y = o[2] | ((unsigned)o[3] << 16);
        v.z = o[4] | ((unsigned)o[5] << 16);
        v.w = o[6] | ((unsigned)o[7] << 16);
        *(uint4*)(msg + (size_t)node * K2 + DIM + d0) = v;
    }
}

// ---------------- SAGE layer: bf16 MFMA, single K=256 GEMM ----------------
__global__ __launch_bounds__(256) void k_sage(const unsigned short* __restrict__ hin,  // [m][256]
                                              const unsigned short* __restrict__ whi,  // [n][256]
                                              const unsigned short* __restrict__ wlo,
                                              const float* __restrict__ bias,
                                              unsigned short* __restrict__ hout) {
    __shared__ unsigned short Ah[128 * 40];   // stride 40 shorts (80 B): 2-way bank alias = free
    __shared__ unsigned short Bh[128 * 40];
    __shared__ unsigned short Bl[128 * 40];
    const int tid = threadIdx.x;
    const int wv = tid >> 6, lane = tid & 63;
    const int m0 = blockIdx.x * 128;
    const int m_off = (wv >> 1) * 64, n_off = (wv & 1) * 64;
    const int l15 = lane & 15, q = lane >> 4;

    f32x4 acc[4][4];
#pragma unroll
    for (int a = 0; a < 4; ++a)
#pragma unroll
        for (int b = 0; b < 4; ++b) acc[a][b] = (f32x4){0.f, 0.f, 0.f, 0.f};

#pragma unroll 1
    for (int kt = 0; kt < 8; ++kt) {
        const int k0 = kt * 32;
#pragma unroll
        for (int i = 0; i < 2; ++i) {
            int idx = tid + i * 256;
            int row = idx >> 2, kq = (idx & 3) * 8;
            int gm = m0 + row;
            uint4 va = make_uint4(0u, 0u, 0u, 0u);
            if (gm < N_NODES) va = *(const uint4*)(hin + (size_t)gm * K2 + k0 + kq);
            *(uint4*)&Ah[row * 40 + kq] = va;
            *(uint4*)&Bh[row * 40 + kq] = *(const uint4*)(whi + (size_t)row * K2 + k0 + kq);
            *(uint4*)&Bl[row * 40 + kq] = *(const uint4*)(wlo + (size_t)row * K2 + k0 + kq);
        }
        __syncthreads();
        bf16x8 hf[4], wh[4], wl[4];
#pragma unroll
        for (int mt = 0; mt < 4; ++mt)
            hf[mt] = *(const bf16x8*)&Ah[(m_off + mt * 16 + l15) * 40 + q * 8];
#pragma unroll
        for (int nt = 0; nt < 4; ++nt) {
            wh[nt] = *(const bf16x8*)&Bh[(n_off + nt * 16 + l15) * 40 + q * 8];
            wl[nt] = *(const bf16x8*)&Bl[(n_off + nt * 16 + l15) * 40 + q * 8];
        }
#pragma unroll
        for (int mt = 0; mt < 4; ++mt)
#pragma unroll
            for (int nt = 0; nt < 4; ++nt) {
                acc[mt][nt] = __builtin_amdgcn_mfma_f32_16x16x32_bf16(wh[nt], hf[mt], acc[mt][nt], 0, 0, 0);
                acc[mt][nt] = __builtin_amdgcn_mfma_f32_16x16x32_bf16(wl[nt], hf[mt], acc[mt][nt], 0, 0, 0);
            }
        __syncthreads();
    }
#pragma unroll
    for (int nt = 0; nt < 4; ++nt) {
        int n = n_off + nt * 16 + q * 4;
        float4 bv = *(const float4*)(bias + n);
#pragma unroll
        for (int mt = 0; mt < 4; ++mt) {
            int m = m0 + m_off + mt * 16 + l15;
            if (m < N_NODES) {
                f32x4 a = acc[mt][nt];
                unsigned short o0 = f2bf(fmaxf(a[0] + bv.x, 0.f));
                unsigned short o1 = f2bf(fmaxf(a[1] + bv.y, 0.f));
                unsigned short o2 = f2bf(fmaxf(a[2] + bv.z, 0.f));
                unsigned short o3 = f2bf(fmaxf(a[3] + bv.w, 0.f));
                uint2 v;
                v.x = o0 | ((unsigned)o1 << 16);
                v.y = o2 | ((unsigned)o3 << 16);
                *(uint2*)(hout + (size_t)m * K2 + n) = v;
            }
        }
    }
}

// ---------------- graph mean-pool (bf16 h, sorted gids) ----------------
__global__ __launch_bounds__(256) void k_pool(const unsigned short* __restrict__ h,
                                              const int* __restrict__ gid,
                                              float* __restrict__ pooled) {
    int d = threadIdx.x & 127;
    int half = threadIdx.x >> 7;
    int n0 = blockIdx.x * 128;
    float acc = 0.f;
    int cur = -1;
    for (int i = half; i < 128; i += 2) {
        int n = n0 + i;
        if (n >= N_NODES) break;
        int g = gid[n];
        if (g != cur) {
            if (cur >= 0) atomicAdd(&pooled[(size_t)cur * DIM + d], acc);
            acc = 0.f;
            cur = g;
        }
        acc += bf2f(h[(size_t)n * K2 + d]);
    }
    if (cur >= 0) atomicAdd(&pooled[(size_t)cur * DIM + d], acc);
}

// ---------------- classifier (fp32) ----------------
__global__ __launch_bounds__(256) void k_final(const float* __restrict__ pooled,
                                               const float* __restrict__ counts,
                                               const float* __restrict__ Wf,
                                               const float* __restrict__ bf,
                                               float* __restrict__ out) {
    int t = blockIdx.x * 256 + threadIdx.x;
    if (t >= N_GRAPHS * CLS) return;
    int g = t / CLS, c = t % CLS;
    float inv = 1.0f / fmaxf(counts[g], 1.0f);
    float s = 0.f;
    for (int k = 0; k < DIM; ++k) s += pooled[(size_t)g * DIM + k] * Wf[k * CLS + c];
    out[t] = s * inv + bf[c];
}

extern "C" void kernel_launch(void* const* d_in, const int* in_sizes, int n_in,
                              void* d_out, int out_size, void* d_ws, size_t ws_size,
                              hipStream_t stream) {
    const float* features = (const float*)d_in[0];
    const int*   esrc     = (const int*)d_in[1];
    const int*   edst     = (const int*)d_in[2];
    const int*   gids     = (const int*)d_in[3];
    const float* bs[3]  = {(const float*)d_in[6], (const float*)d_in[9], (const float*)d_in[12]};
    const float* Wf = (const float*)d_in[13];
    const float* bfv = (const float*)d_in[14];
    float* out = (float*)d_out;

    // ---- workspace layout ----
    int* deg_i  = (int*)d_ws;            // 50000 used; +gcount covered by same memset
    int* gcount = deg_i + 50000;         // 8
    int* rowptr = deg_i + 50048;         // 50064
    int* cursor = rowptr + 50064;        // 50048
    int* bsum   = cursor + 50048;        // 256
    int* boff   = bsum + 256;            // 256
    int* eidx   = boff + 256;            // 800000
    int2* stag  = (int2*)(eidx + 800000);        // 8*131072 int2 = 8 MB
    float* pooled = (float*)(stag + (size_t)NPART * PCAP);   // 16384
    float* counts = pooled + N_GRAPHS * DIM;     // 128
    unsigned short* C0  = (unsigned short*)(counts + 128);   // 50000*256 bf16
    unsigned short* C1  = C0 + (size_t)N_NODES * K2;
    unsigned short* C2  = C1 + (size_t)N_NODES * K2;
    unsigned short* Whi = C2 + (size_t)N_NODES * K2;         // 3*128*256
    unsigned short* Wlo = Whi + 3 * DIM * K2;

    hipMemsetAsync(deg_i, 0, 50048 * sizeof(int), stream);
    hipMemsetAsync(pooled, 0, N_GRAPHS * DIM * sizeof(float), stream);

    // CSR build: bin -> deg -> scan -> fill
    k_bin<<<NBIN, 256, 0, stream>>>(esrc, edst, stag, gcount);
    k_deg2<<<NPART * 64, 256, 0, stream>>>(stag, gcount, deg_i);
    k_scan_part<<<NB_SCAN, 256, 0, stream>>>(deg_i, rowptr, bsum);
    k_scan_top<<<1, 256, 0, stream>>>(bsum, boff, rowptr, gids, counts);
    k_scan_add<<<NB_SCAN, 256, 0, stream>>>(rowptr, boff, cursor);
    k_fill2<<<NPART * 64, 256, 0, stream>>>(stag, gcount, cursor, eidx);
    k_cast<<<(N_NODES * 16 + 255) / 256, 256, 0, stream>>>(features, C0);
    k_prep_w<<<(3 * DIM * K2 + 255) / 256, 256, 0, stream>>>(
        (const float*)d_in[4], (const float*)d_in[5],
        (const float*)d_in[7], (const float*)d_in[8],
        (const float*)d_in[10], (const float*)d_in[11], Whi, Wlo);

    unsigned short* C[4] = {C0, C1, C2, C0};
    for (int l = 0; l < 3; ++l) {
        k_gather<<<(N_NODES * 64 + 255) / 256, 256, 0, stream>>>(C[l], rowptr, eidx, C[l]);
        k_sage<<<(N_NODES + 127) / 128, 256, 0, stream>>>(
            C[l], Whi + (size_t)l * DIM * K2, Wlo + (size_t)l * DIM * K2, bs[l], C[l + 1]);
    }

    k_pool<<<(N_NODES + 127) / 128, 256, 0, stream>>>(C0, gids, pooled);
    k_final<<<(N_GRAPHS * CLS + 255) / 256, 256, 0, stream>>>(pooled, counts, Wf, bfv, out);
}

// Round 9
// 419.211 us; speedup vs baseline: 1.0621x; 1.0353x over previous
//
#include <hip/hip_runtime.h>

#define N_NODES  50000
#define N_EDGES  800000
#define N_GRAPHS 128
#define DIM      128
#define K2       256
#define CLS      10
#define NB_SCAN  ((N_NODES + 255) / 256)   // 196
#define NPART    8
#define PSIZE    (N_NODES / NPART)          // 6250
#define NBIN     400
#define CHUNK    (N_EDGES / NBIN)           // 2000
#define PCAP     131072

typedef __attribute__((ext_vector_type(8))) _Float16 f16x8;
typedef __attribute__((ext_vector_type(4))) float f32x4;

union U4H8 { uint4 u; _Float16 h[8]; };
union U2H4 { uint2 u; _Float16 h[4]; };

__device__ inline float h2f(unsigned short s) {
    union { unsigned short u; _Float16 h; } c; c.u = s; return (float)c.h;
}

// ---------------- phase A: bin edges by dst partition (wave-aggregated LDS atomics) ----------------
__global__ __launch_bounds__(256) void k_bin(const int* __restrict__ src, const int* __restrict__ dst,
                                             int2* __restrict__ stag, int* __restrict__ gcount) {
    __shared__ int lcount[NPART];
    __shared__ int lbase[NPART];
    const int tid = threadIdx.x;
    const int lane = tid & 63;
    const int lo = blockIdx.x * CHUNK;
    if (tid < NPART) lcount[tid] = 0;
    __syncthreads();
    for (int i = lo + tid; i < lo + CHUNK; i += 256) {
        int p = dst[i] / PSIZE;
#pragma unroll
        for (int q = 0; q < NPART; ++q) {
            unsigned long long m = __ballot(p == q);
            if (p == q) {
                int leader = __ffsll((long long)m) - 1;
                if (lane == leader) atomicAdd(&lcount[q], (int)__popcll(m));
            }
        }
    }
    __syncthreads();
    if (tid < NPART) {
        lbase[tid] = atomicAdd(&gcount[tid], lcount[tid]);
        lcount[tid] = 0;   // reuse as cursor
    }
    __syncthreads();
    for (int i = lo + tid; i < lo + CHUNK; i += 256) {
        int d = dst[i];
        int p = d / PSIZE;
        int slot = 0;
#pragma unroll
        for (int q = 0; q < NPART; ++q) {
            unsigned long long m = __ballot(p == q);
            if (p == q) {
                int leader = __ffsll((long long)m) - 1;
                int rank = (int)__popcll(m & ((1ull << lane) - 1ull));
                int base;
                if (lane == leader) base = atomicAdd(&lcount[q], (int)__popcll(m));
                base = __shfl(base, leader);
                slot = base + rank;
            }
        }
        stag[(size_t)p * PCAP + lbase[p] + slot] = make_int2(src[i], d);
    }
}

// ---------------- phase B: degree count from staged pairs (XCD-local) ----------------
__global__ __launch_bounds__(256) void k_deg2(const int2* __restrict__ stag, const int* __restrict__ gcount,
                                              int* __restrict__ deg) {
    const int part = blockIdx.x & (NPART - 1);
    const int blk = blockIdx.x >> 3;
    const int n = gcount[part];
    const int2* s = stag + (size_t)part * PCAP;
    for (int i = blk * 256 + threadIdx.x; i < n; i += 64 * 256)
        atomicAdd(&deg[s[i].y], 1);
}

// ---------------- phase D: CSR fill from staged pairs (XCD-local) ----------------
__global__ __launch_bounds__(256) void k_fill2(const int2* __restrict__ stag, const int* __restrict__ gcount,
                                               int* __restrict__ cursor, int* __restrict__ eidx) {
    const int part = blockIdx.x & (NPART - 1);
    const int blk = blockIdx.x >> 3;
    const int n = gcount[part];
    const int2* s = stag + (size_t)part * PCAP;
    for (int i = blk * 256 + threadIdx.x; i < n; i += 64 * 256) {
        int2 e = s[i];
        int pos = atomicAdd(&cursor[e.y], 1);
        eidx[pos] = e.x;
    }
}

// ---------------- parallel 3-phase scan ----------------
__global__ __launch_bounds__(256) void k_scan_part(const int* __restrict__ deg,
                                                   int* __restrict__ rowptr, int* __restrict__ bsum) {
    __shared__ int s[256];
    const int tid = threadIdx.x;
    const int i = blockIdx.x * 256 + tid;
    int v = (i < N_NODES) ? deg[i] : 0;
    s[tid] = v;
    __syncthreads();
    for (int off = 1; off < 256; off <<= 1) {
        int add = (tid >= off) ? s[tid - off] : 0;
        __syncthreads();
        s[tid] += add;
        __syncthreads();
    }
    if (i < N_NODES) rowptr[i] = s[tid] - v;
    if (tid == 255) bsum[blockIdx.x] = s[255];
}

__global__ __launch_bounds__(256) void k_scan_top(const int* __restrict__ bsum, int* __restrict__ boff,
                                                  int* __restrict__ rowptr,
                                                  const int* __restrict__ gid, float* __restrict__ counts) {
    __shared__ int s[256];
    const int tid = threadIdx.x;
    if (tid < N_GRAPHS) {
        int g = tid;
        int lo = 0, hi = N_NODES;
        while (lo < hi) { int mid = (lo + hi) >> 1; if (gid[mid] < g) lo = mid + 1; else hi = mid; }
        int start = lo;
        lo = 0; hi = N_NODES;
        while (lo < hi) { int mid = (lo + hi) >> 1; if (gid[mid] <= g) lo = mid + 1; else hi = mid; }
        counts[g] = (float)(lo - start);
    }
    int v = (tid < NB_SCAN) ? bsum[tid] : 0;
    s[tid] = v;
    __syncthreads();
    for (int off = 1; off < 256; off <<= 1) {
        int add = (tid >= off) ? s[tid - off] : 0;
        __syncthreads();
        s[tid] += add;
        __syncthreads();
    }
    if (tid < NB_SCAN) boff[tid] = s[tid] - v;
    if (tid == 0) rowptr[N_NODES] = N_EDGES;
}

__global__ __launch_bounds__(256) void k_scan_add(int* __restrict__ rowptr, const int* __restrict__ boff,
                                                  int* __restrict__ cursor) {
    const int i = blockIdx.x * 256 + threadIdx.x;
    if (i < N_NODES) {
        int r = rowptr[i] + boff[blockIdx.x];
        rowptr[i] = r;
        cursor[i] = r;
    }
}

// ---------------- features fp32 -> fp16 hcat0 h-part ----------------
__global__ __launch_bounds__(256) void k_cast(const float* __restrict__ f, unsigned short* __restrict__ c0) {
    int t = blockIdx.x * 256 + threadIdx.x;   // one per 8 elems
    if (t >= N_NODES * 16) return;
    int row = t >> 4, c8 = (t & 15) * 8;
    const float* p = f + (size_t)row * DIM + c8;
    float4 a = *(const float4*)p;
    float4 b = *(const float4*)(p + 4);
    U4H8 v;
    v.h[0] = (_Float16)a.x; v.h[1] = (_Float16)a.y;
    v.h[2] = (_Float16)a.z; v.h[3] = (_Float16)a.w;
    v.h[4] = (_Float16)b.x; v.h[5] = (_Float16)b.y;
    v.h[6] = (_Float16)b.z; v.h[7] = (_Float16)b.w;
    *(uint4*)(c0 + (size_t)row * K2 + c8) = v.u;
}

// ---------------- weights: transpose + concat -> fp16 Wt[l][n][k0..255] ----------------
__global__ __launch_bounds__(256) void k_prep_w(const float* __restrict__ Ws0, const float* __restrict__ Wn0,
                                                const float* __restrict__ Ws1, const float* __restrict__ Wn1,
                                                const float* __restrict__ Ws2, const float* __restrict__ Wn2,
                                                unsigned short* __restrict__ wt) {
    int t = blockIdx.x * 256 + threadIdx.x;
    if (t >= 3 * DIM * K2) return;
    int l = t / (DIM * K2), r = t % (DIM * K2);
    int n = r / K2, k = r % K2;
    const float* Ws = (l == 0) ? Ws0 : (l == 1) ? Ws1 : Ws2;
    const float* Wn = (l == 0) ? Wn0 : (l == 1) ? Wn1 : Wn2;
    float w = (k < DIM) ? Ws[k * DIM + n] : Wn[(k - DIM) * DIM + n];
    union { unsigned short u; _Float16 h; } c;
    c.h = (_Float16)w;
    wt[t] = c.u;
}

// ---------------- gather: one wave per node, fp16 rows, fp32 accum, 8 edges in flight ----------------
__global__ __launch_bounds__(256) void k_gather(const unsigned short* __restrict__ h,
                                                const int* __restrict__ rowptr,
                                                const int* __restrict__ eidx,
                                                unsigned short* __restrict__ msg) {
    const int node = (blockIdx.x * 256 + threadIdx.x) >> 6;
    const int lane = threadIdx.x & 63;
    if (node >= N_NODES) return;
    const int epar = lane >> 4;        // which of 4 edge slots
    const int d0 = (lane & 15) * 8;    // 8 fp16 per lane = 16 B
    const int beg = rowptr[node], end = rowptr[node + 1];
    float acc[8] = {0.f, 0.f, 0.f, 0.f, 0.f, 0.f, 0.f, 0.f};
    int j = beg + epar;
    for (; j + 4 < end; j += 8) {      // 8 edges in flight per wave
        int s0 = eidx[j], s1 = eidx[j + 4];
        U4H8 v0, v1;
        v0.u = *(const uint4*)(h + (size_t)s0 * K2 + d0);
        v1.u = *(const uint4*)(h + (size_t)s1 * K2 + d0);
#pragma unroll
        for (int i = 0; i < 8; ++i) acc[i] += (float)v0.h[i] + (float)v1.h[i];
    }
    if (j < end) {
        U4H8 v0;
        v0.u = *(const uint4*)(h + (size_t)eidx[j] * K2 + d0);
#pragma unroll
        for (int i = 0; i < 8; ++i) acc[i] += (float)v0.h[i];
    }
#pragma unroll
    for (int i = 0; i < 8; ++i) {
        acc[i] += __shfl_xor(acc[i], 16);
        acc[i] += __shfl_xor(acc[i], 32);
    }
    if (epar == 0) {
        float inv = (end > beg) ? 1.0f / (float)(end - beg) : 0.f;
        U4H8 o;
#pragma unroll
        for (int i = 0; i < 8; ++i) o.h[i] = (_Float16)(acc[i] * inv);
        *(uint4*)(msg + (size_t)node * K2 + DIM + d0) = o.u;
    }
}

// ---------------- SAGE layer: fp16 MFMA, single K=256 GEMM, single plane ----------------
__global__ __launch_bounds__(256) void k_sage(const unsigned short* __restrict__ hin,  // [m][256] fp16
                                              const unsigned short* __restrict__ wt,   // [n][256] fp16
                                              const float* __restrict__ bias,
                                              unsigned short* __restrict__ hout) {
    __shared__ _Float16 Ah[128 * 40];   // stride 40 halfs (80 B): 2-way bank alias = free
    __shared__ _Float16 Bw[128 * 40];
    const int tid = threadIdx.x;
    const int wv = tid >> 6, lane = tid & 63;
    const int m0 = blockIdx.x * 128;
    const int m_off = (wv >> 1) * 64, n_off = (wv & 1) * 64;
    const int l15 = lane & 15, q = lane >> 4;

    f32x4 acc[4][4];
#pragma unroll
    for (int a = 0; a < 4; ++a)
#pragma unroll
        for (int b = 0; b < 4; ++b) acc[a][b] = (f32x4){0.f, 0.f, 0.f, 0.f};

#pragma unroll 1
    for (int kt = 0; kt < 8; ++kt) {
        const int k0 = kt * 32;
#pragma unroll
        for (int i = 0; i < 2; ++i) {
            int idx = tid + i * 256;
            int row = idx >> 2, kq = (idx & 3) * 8;
            int gm = m0 + row;
            uint4 va = make_uint4(0u, 0u, 0u, 0u);
            if (gm < N_NODES) va = *(const uint4*)(hin + (size_t)gm * K2 + k0 + kq);
            *(uint4*)&Ah[row * 40 + kq] = va;
            *(uint4*)&Bw[row * 40 + kq] = *(const uint4*)(wt + (size_t)row * K2 + k0 + kq);
        }
        __syncthreads();
        f16x8 hf[4], wf[4];
#pragma unroll
        for (int mt = 0; mt < 4; ++mt)
            hf[mt] = *(const f16x8*)&Ah[(m_off + mt * 16 + l15) * 40 + q * 8];
#pragma unroll
        for (int nt = 0; nt < 4; ++nt)
            wf[nt] = *(const f16x8*)&Bw[(n_off + nt * 16 + l15) * 40 + q * 8];
#pragma unroll
        for (int mt = 0; mt < 4; ++mt)
#pragma unroll
            for (int nt = 0; nt < 4; ++nt)
                acc[mt][nt] = __builtin_amdgcn_mfma_f32_16x16x32_f16(wf[nt], hf[mt], acc[mt][nt], 0, 0, 0);
        __syncthreads();
    }
    // epilogue: lane holds row m (per mt), 4 consecutive cols -> 8 B stores
#pragma unroll
    for (int nt = 0; nt < 4; ++nt) {
        int n = n_off + nt * 16 + q * 4;
        float4 bv = *(const float4*)(bias + n);
#pragma unroll
        for (int mt = 0; mt < 4; ++mt) {
            int m = m0 + m_off + mt * 16 + l15;
            if (m < N_NODES) {
                f32x4 a = acc[mt][nt];
                U2H4 v;
                v.h[0] = (_Float16)fmaxf(a[0] + bv.x, 0.f);
                v.h[1] = (_Float16)fmaxf(a[1] + bv.y, 0.f);
                v.h[2] = (_Float16)fmaxf(a[2] + bv.z, 0.f);
                v.h[3] = (_Float16)fmaxf(a[3] + bv.w, 0.f);
                *(uint2*)(hout + (size_t)m * K2 + n) = v.u;
            }
        }
    }
}

// ---------------- graph mean-pool (fp16 h, sorted gids) ----------------
__global__ __launch_bounds__(256) void k_pool(const unsigned short* __restrict__ h,
                                              const int* __restrict__ gid,
                                              float* __restrict__ pooled) {
    int d = threadIdx.x & 127;
    int half = threadIdx.x >> 7;
    int n0 = blockIdx.x * 128;
    float acc = 0.f;
    int cur = -1;
    for (int i = half; i < 128; i += 2) {
        int n = n0 + i;
        if (n >= N_NODES) break;
        int g = gid[n];
        if (g != cur) {
            if (cur >= 0) atomicAdd(&pooled[(size_t)cur * DIM + d], acc);
            acc = 0.f;
            cur = g;
        }
        acc += h2f(h[(size_t)n * K2 + d]);
    }
    if (cur >= 0) atomicAdd(&pooled[(size_t)cur * DIM + d], acc);
}

// ---------------- classifier (fp32) ----------------
__global__ __launch_bounds__(256) void k_final(const float* __restrict__ pooled,
                                               const float* __restrict__ counts,
                                               const float* __restrict__ Wf,
                                               const float* __restrict__ bf,
                                               float* __restrict__ out) {
    int t = blockIdx.x * 256 + threadIdx.x;
    if (t >= N_GRAPHS * CLS) return;
    int g = t / CLS, c = t % CLS;
    float inv = 1.0f / fmaxf(counts[g], 1.0f);
    float s = 0.f;
    for (int k = 0; k < DIM; ++k) s += pooled[(size_t)g * DIM + k] * Wf[k * CLS + c];
    out[t] = s * inv + bf[c];
}

extern "C" void kernel_launch(void* const* d_in, const int* in_sizes, int n_in,
                              void* d_out, int out_size, void* d_ws, size_t ws_size,
                              hipStream_t stream) {
    const float* features = (const float*)d_in[0];
    const int*   esrc     = (const int*)d_in[1];
    const int*   edst     = (const int*)d_in[2];
    const int*   gids     = (const int*)d_in[3];
    const float* bs[3]  = {(const float*)d_in[6], (const float*)d_in[9], (const float*)d_in[12]};
    const float* Wf = (const float*)d_in[13];
    const float* bfv = (const float*)d_in[14];
    float* out = (float*)d_out;

    // ---- workspace layout ----
    int* deg_i  = (int*)d_ws;            // 50000 used; +gcount covered by same memset
    int* gcount = deg_i + 50000;         // 8
    int* rowptr = deg_i + 50048;         // 50064
    int* cursor = rowptr + 50064;        // 50048
    int* bsum   = cursor + 50048;        // 256
    int* boff   = bsum + 256;            // 256
    int* eidx   = boff + 256;            // 800000
    int2* stag  = (int2*)(eidx + 800000);        // 8*131072 int2 = 8 MB
    float* pooled = (float*)(stag + (size_t)NPART * PCAP);   // 16384
    float* counts = pooled + N_GRAPHS * DIM;     // 128
    unsigned short* C0 = (unsigned short*)(counts + 128);    // 50000*256 fp16
    unsigned short* C1 = C0 + (size_t)N_NODES * K2;
    unsigned short* C2 = C1 + (size_t)N_NODES * K2;
    unsigned short* Wt = C2 + (size_t)N_NODES * K2;          // 3*128*256 fp16

    hipMemsetAsync(deg_i, 0, 50048 * sizeof(int), stream);
    hipMemsetAsync(pooled, 0, N_GRAPHS * DIM * sizeof(float), stream);

    // CSR build: bin -> deg -> scan -> fill
    k_bin<<<NBIN, 256, 0, stream>>>(esrc, edst, stag, gcount);
    k_deg2<<<NPART * 64, 256, 0, stream>>>(stag, gcount, deg_i);
    k_scan_part<<<NB_SCAN, 256, 0, stream>>>(deg_i, rowptr, bsum);
    k_scan_top<<<1, 256, 0, stream>>>(bsum, boff, rowptr, gids, counts);
    k_scan_add<<<NB_SCAN, 256, 0, stream>>>(rowptr, boff, cursor);
    k_fill2<<<NPART * 64, 256, 0, stream>>>(stag, gcount, cursor, eidx);
    k_cast<<<(N_NODES * 16 + 255) / 256, 256, 0, stream>>>(features, C0);
    k_prep_w<<<(3 * DIM * K2 + 255) / 256, 256, 0, stream>>>(
        (const float*)d_in[4], (const float*)d_in[5],
        (const float*)d_in[7], (const float*)d_in[8],
        (const float*)d_in[10], (const float*)d_in[11], Wt);

    unsigned short* C[4] = {C0, C1, C2, C0};
    for (int l = 0; l < 3; ++l) {
        k_gather<<<(N_NODES * 64 + 255) / 256, 256, 0, stream>>>(C[l], rowptr, eidx, C[l]);
        k_sage<<<(N_NODES + 127) / 128, 256, 0, stream>>>(
            C[l], Wt + (size_t)l * DIM * K2, bs[l], C[l + 1]);
    }

    k_pool<<<(N_NODES + 127) / 128, 256, 0, stream>>>(C0, gids, pooled);
    k_final<<<(N_GRAPHS * CLS + 255) / 256, 256, 0, stream>>>(pooled, counts, Wf, bfv, out);
}

// Round 10
// 377.292 us; speedup vs baseline: 1.1801x; 1.1111x over previous
//
#include <hip/hip_runtime.h>

#define N_NODES  50000
#define N_EDGES  800000
#define N_GRAPHS 128
#define DIM      128
#define K2       256
#define CLS      10
#define NB_SCAN  ((N_NODES + 255) / 256)   // 196
#define NPART    8
#define PSIZE    (N_NODES / NPART)          // 6250
#define NBIN     400
#define CHUNK    (N_EDGES / NBIN)           // 2000
#define PCAP     131072

typedef __attribute__((ext_vector_type(8))) _Float16 f16x8;
typedef __attribute__((ext_vector_type(4))) float f32x4;
typedef __attribute__((ext_vector_type(2))) float f32x2;

union U4H8 { uint4 u; _Float16 h[8]; };
union U2H4 { uint2 u; _Float16 h[4]; };

__device__ inline float h2f(unsigned short s) {
    union { unsigned short u; _Float16 h; } c; c.u = s; return (float)c.h;
}

// ---------------- init: cast features (fp16 + fp8), prep weights, zero deg/gcount/pooled, counts ----------------
__global__ __launch_bounds__(256) void k_init(const float* __restrict__ f,
                                              unsigned short* __restrict__ c0, unsigned char* __restrict__ f8,
                                              const float* __restrict__ Ws0, const float* __restrict__ Wn0,
                                              const float* __restrict__ Ws1, const float* __restrict__ Wn1,
                                              const float* __restrict__ Ws2, const float* __restrict__ Wn2,
                                              unsigned short* __restrict__ wt,
                                              int* __restrict__ zero_region, float* __restrict__ pooled,
                                              const int* __restrict__ gid, float* __restrict__ counts) {
    long long gi = (long long)blockIdx.x * 256 + threadIdx.x;
    if (gi < 800000) {   // features: 8 elems/thread -> fp16 row c0 + fp8 row f8
        int t = (int)gi;
        int row = t >> 4, c8 = (t & 15) * 8;
        const float* p = f + (size_t)row * DIM + c8;
        float4 a = *(const float4*)p;
        float4 b = *(const float4*)(p + 4);
        U4H8 v;
        v.h[0] = (_Float16)a.x; v.h[1] = (_Float16)a.y;
        v.h[2] = (_Float16)a.z; v.h[3] = (_Float16)a.w;
        v.h[4] = (_Float16)b.x; v.h[5] = (_Float16)b.y;
        v.h[6] = (_Float16)b.z; v.h[7] = (_Float16)b.w;
        *(uint4*)(c0 + (size_t)row * K2 + c8) = v.u;
        int p0 = __builtin_amdgcn_cvt_pk_fp8_f32(a.x, a.y, 0, false);
        p0 = __builtin_amdgcn_cvt_pk_fp8_f32(a.z, a.w, p0, true);
        int p1 = __builtin_amdgcn_cvt_pk_fp8_f32(b.x, b.y, 0, false);
        p1 = __builtin_amdgcn_cvt_pk_fp8_f32(b.z, b.w, p1, true);
        *(uint2*)(f8 + (size_t)row * DIM + c8) = make_uint2((unsigned)p0, (unsigned)p1);
        return;
    }
    gi -= 800000;
    if (gi < 3 * DIM * K2) {   // weights: transpose+concat -> fp16 [l][n][k]
        int t = (int)gi;
        int l = t / (DIM * K2), r = t % (DIM * K2);
        int n = r / K2, k = r % K2;
        const float* Ws = (l == 0) ? Ws0 : (l == 1) ? Ws1 : Ws2;
        const float* Wn = (l == 0) ? Wn0 : (l == 1) ? Wn1 : Wn2;
        float w = (k < DIM) ? Ws[k * DIM + n] : Wn[(k - DIM) * DIM + n];
        union { unsigned short u; _Float16 h; } c;
        c.h = (_Float16)w;
        wt[t] = c.u;
        return;
    }
    gi -= 3 * DIM * K2;
    if (gi < 50056) { zero_region[gi] = 0; return; }   // deg + gcount
    gi -= 50056;
    if (gi < N_GRAPHS * DIM) { pooled[gi] = 0.f; return; }
    gi -= (long long)N_GRAPHS * DIM;
    if (gi < N_GRAPHS) {   // graph counts via binary search (gid sorted)
        int g = (int)gi;
        int lo = 0, hi = N_NODES;
        while (lo < hi) { int mid = (lo + hi) >> 1; if (gid[mid] < g) lo = mid + 1; else hi = mid; }
        int start = lo;
        lo = 0; hi = N_NODES;
        while (lo < hi) { int mid = (lo + hi) >> 1; if (gid[mid] <= g) lo = mid + 1; else hi = mid; }
        counts[g] = (float)(lo - start);
    }
}
#define INIT_THREADS (800000 + 3 * DIM * K2 + 50056 + N_GRAPHS * DIM + N_GRAPHS)

// ---------------- bin edges by dst partition (wave-aggregated) + global degree count ----------------
__global__ __launch_bounds__(256) void k_bin(const int* __restrict__ src, const int* __restrict__ dst,
                                             int2* __restrict__ stag, int* __restrict__ gcount,
                                             int* __restrict__ deg) {
    __shared__ int lcount[NPART];
    __shared__ int lbase[NPART];
    const int tid = threadIdx.x;
    const int lane = tid & 63;
    const int lo = blockIdx.x * CHUNK;
    if (tid < NPART) lcount[tid] = 0;
    __syncthreads();
    for (int i = lo + tid; i < lo + CHUNK; i += 256) {
        int d = dst[i];
        atomicAdd(&deg[d], 1);
        int p = d / PSIZE;
#pragma unroll
        for (int q = 0; q < NPART; ++q) {
            unsigned long long m = __ballot(p == q);
            if (p == q) {
                int leader = __ffsll((long long)m) - 1;
                if (lane == leader) atomicAdd(&lcount[q], (int)__popcll(m));
            }
        }
    }
    __syncthreads();
    if (tid < NPART) {
        lbase[tid] = atomicAdd(&gcount[tid], lcount[tid]);
        lcount[tid] = 0;   // reuse as cursor
    }
    __syncthreads();
    for (int i = lo + tid; i < lo + CHUNK; i += 256) {
        int d = dst[i];
        int p = d / PSIZE;
        int slot = 0;
#pragma unroll
        for (int q = 0; q < NPART; ++q) {
            unsigned long long m = __ballot(p == q);
            if (p == q) {
                int leader = __ffsll((long long)m) - 1;
                int rank = (int)__popcll(m & ((1ull << lane) - 1ull));
                int base;
                if (lane == leader) base = atomicAdd(&lcount[q], (int)__popcll(m));
                base = __shfl(base, leader);
                slot = base + rank;
            }
        }
        stag[(size_t)p * PCAP + lbase[p] + slot] = make_int2(src[i], d);
    }
}

// ---------------- CSR fill from staged pairs (XCD-local) ----------------
__global__ __launch_bounds__(256) void k_fill2(const int2* __restrict__ stag, const int* __restrict__ gcount,
                                               int* __restrict__ cursor, int* __restrict__ eidx) {
    const int part = blockIdx.x & (NPART - 1);
    const int blk = blockIdx.x >> 3;
    const int n = gcount[part];
    const int2* s = stag + (size_t)part * PCAP;
    for (int i = blk * 256 + threadIdx.x; i < n; i += 64 * 256) {
        int2 e = s[i];
        int pos = atomicAdd(&cursor[e.y], 1);
        eidx[pos] = e.x;
    }
}

// ---------------- scan phase 1: per-block local exclusive scan ----------------
__global__ __launch_bounds__(256) void k_scan_part(const int* __restrict__ deg,
                                                   int* __restrict__ rowptr, int* __restrict__ bsum) {
    __shared__ int s[256];
    const int tid = threadIdx.x;
    const int i = blockIdx.x * 256 + tid;
    int v = (i < N_NODES) ? deg[i] : 0;
    s[tid] = v;
    __syncthreads();
    for (int off = 1; off < 256; off <<= 1) {
        int add = (tid >= off) ? s[tid - off] : 0;
        __syncthreads();
        s[tid] += add;
        __syncthreads();
    }
    if (i < N_NODES) rowptr[i] = s[tid] - v;
    if (tid == 255) bsum[blockIdx.x] = s[255];
}

// ---------------- scan phase 2: redundant top-scan per block + add offsets ----------------
__global__ __launch_bounds__(256) void k_scan_add(int* __restrict__ rowptr, const int* __restrict__ bsum,
                                                  int* __restrict__ cursor) {
    __shared__ int s[256];
    __shared__ int off_sh;
    const int tid = threadIdx.x;
    int v = (tid < NB_SCAN) ? bsum[tid] : 0;
    s[tid] = v;
    __syncthreads();
    for (int off = 1; off < 256; off <<= 1) {
        int add = (tid >= off) ? s[tid - off] : 0;
        __syncthreads();
        s[tid] += add;
        __syncthreads();
    }
    if (tid == blockIdx.x) off_sh = s[tid] - v;   // exclusive offset for this block
    __syncthreads();
    const int i = blockIdx.x * 256 + tid;
    if (i < N_NODES) {
        int r = rowptr[i] + off_sh;
        rowptr[i] = r;
        cursor[i] = r;
    }
    if (blockIdx.x == 0 && tid == 0) rowptr[N_NODES] = N_EDGES;
}

// ---------------- gather: one wave per node, fp8 rows, fp32 accum, 8 edges in flight ----------------
__global__ __launch_bounds__(256) void k_gather(const unsigned char* __restrict__ h8,
                                                const int* __restrict__ rowptr,
                                                const int* __restrict__ eidx,
                                                unsigned short* __restrict__ msg) {
    const int node = (blockIdx.x * 256 + threadIdx.x) >> 6;
    const int lane = threadIdx.x & 63;
    if (node >= N_NODES) return;
    const int epar = lane >> 4;        // which of 4 edge slots
    const int d0 = (lane & 15) * 8;    // 8 fp8 per lane = 8 B
    const int beg = rowptr[node], end = rowptr[node + 1];
    float acc[8] = {0.f, 0.f, 0.f, 0.f, 0.f, 0.f, 0.f, 0.f};
    int j = beg + epar;
    for (; j + 4 < end; j += 8) {      // 8 edges in flight per wave
        int s0 = eidx[j], s1 = eidx[j + 4];
        uint2 v0 = *(const uint2*)(h8 + (size_t)s0 * DIM + d0);
        uint2 v1 = *(const uint2*)(h8 + (size_t)s1 * DIM + d0);
        f32x2 e;
        e = __builtin_amdgcn_cvt_pk_f32_fp8(v0.x, false); acc[0] += e[0]; acc[1] += e[1];
        e = __builtin_amdgcn_cvt_pk_f32_fp8(v0.x, true);  acc[2] += e[0]; acc[3] += e[1];
        e = __builtin_amdgcn_cvt_pk_f32_fp8(v0.y, false); acc[4] += e[0]; acc[5] += e[1];
        e = __builtin_amdgcn_cvt_pk_f32_fp8(v0.y, true);  acc[6] += e[0]; acc[7] += e[1];
        e = __builtin_amdgcn_cvt_pk_f32_fp8(v1.x, false); acc[0] += e[0]; acc[1] += e[1];
        e = __builtin_amdgcn_cvt_pk_f32_fp8(v1.x, true);  acc[2] += e[0]; acc[3] += e[1];
        e = __builtin_amdgcn_cvt_pk_f32_fp8(v1.y, false); acc[4] += e[0]; acc[5] += e[1];
        e = __builtin_amdgcn_cvt_pk_f32_fp8(v1.y, true);  acc[6] += e[0]; acc[7] += e[1];
    }
    if (j < end) {
        uint2 v0 = *(const uint2*)(h8 + (size_t)eidx[j] * DIM + d0);
        f32x2 e;
        e = __builtin_amdgcn_cvt_pk_f32_fp8(v0.x, false); acc[0] += e[0]; acc[1] += e[1];
        e = __builtin_amdgcn_cvt_pk_f32_fp8(v0.x, true);  acc[2] += e[0]; acc[3] += e[1];
        e = __builtin_amdgcn_cvt_pk_f32_fp8(v0.y, false); acc[4] += e[0]; acc[5] += e[1];
        e = __builtin_amdgcn_cvt_pk_f32_fp8(v0.y, true);  acc[6] += e[0]; acc[7] += e[1];
    }
#pragma unroll
    for (int i = 0; i < 8; ++i) {
        acc[i] += __shfl_xor(acc[i], 16);
        acc[i] += __shfl_xor(acc[i], 32);
    }
    if (epar == 0) {
        float inv = (end > beg) ? 1.0f / (float)(end - beg) : 0.f;
        U4H8 o;
#pragma unroll
        for (int i = 0; i < 8; ++i) o.h[i] = (_Float16)(acc[i] * inv);
        *(uint4*)(msg + (size_t)node * K2 + DIM + d0) = o.u;
    }
}

// ---------------- SAGE layer: fp16 MFMA K=256; epilogue writes fp16 h + fp8 shadow ----------------
__global__ __launch_bounds__(256) void k_sage(const unsigned short* __restrict__ hin,  // [m][256] fp16
                                              const unsigned short* __restrict__ wt,   // [n][256] fp16
                                              const float* __restrict__ bias,
                                              unsigned short* __restrict__ hout,
                                              unsigned char* __restrict__ hout8) {
    __shared__ _Float16 Ah[128 * 40];   // stride 40 halfs (80 B): 2-way bank alias = free
    __shared__ _Float16 Bw[128 * 40];
    const int tid = threadIdx.x;
    const int wv = tid >> 6, lane = tid & 63;
    const int m0 = blockIdx.x * 128;
    const int m_off = (wv >> 1) * 64, n_off = (wv & 1) * 64;
    const int l15 = lane & 15, q = lane >> 4;

    f32x4 acc[4][4];
#pragma unroll
    for (int a = 0; a < 4; ++a)
#pragma unroll
        for (int b = 0; b < 4; ++b) acc[a][b] = (f32x4){0.f, 0.f, 0.f, 0.f};

#pragma unroll 1
    for (int kt = 0; kt < 8; ++kt) {
        const int k0 = kt * 32;
#pragma unroll
        for (int i = 0; i < 2; ++i) {
            int idx = tid + i * 256;
            int row = idx >> 2, kq = (idx & 3) * 8;
            int gm = m0 + row;
            uint4 va = make_uint4(0u, 0u, 0u, 0u);
            if (gm < N_NODES) va = *(const uint4*)(hin + (size_t)gm * K2 + k0 + kq);
            *(uint4*)&Ah[row * 40 + kq] = va;
            *(uint4*)&Bw[row * 40 + kq] = *(const uint4*)(wt + (size_t)row * K2 + k0 + kq);
        }
        __syncthreads();
        f16x8 hf[4], wf[4];
#pragma unroll
        for (int mt = 0; mt < 4; ++mt)
            hf[mt] = *(const f16x8*)&Ah[(m_off + mt * 16 + l15) * 40 + q * 8];
#pragma unroll
        for (int nt = 0; nt < 4; ++nt)
            wf[nt] = *(const f16x8*)&Bw[(n_off + nt * 16 + l15) * 40 + q * 8];
#pragma unroll
        for (int mt = 0; mt < 4; ++mt)
#pragma unroll
            for (int nt = 0; nt < 4; ++nt)
                acc[mt][nt] = __builtin_amdgcn_mfma_f32_16x16x32_f16(wf[nt], hf[mt], acc[mt][nt], 0, 0, 0);
        __syncthreads();
    }
#pragma unroll
    for (int nt = 0; nt < 4; ++nt) {
        int n = n_off + nt * 16 + q * 4;
        float4 bv = *(const float4*)(bias + n);
#pragma unroll
        for (int mt = 0; mt < 4; ++mt) {
            int m = m0 + m_off + mt * 16 + l15;
            if (m < N_NODES) {
                f32x4 a = acc[mt][nt];
                float r0 = fmaxf(a[0] + bv.x, 0.f);
                float r1 = fmaxf(a[1] + bv.y, 0.f);
                float r2 = fmaxf(a[2] + bv.z, 0.f);
                float r3 = fmaxf(a[3] + bv.w, 0.f);
                U2H4 v;
                v.h[0] = (_Float16)r0; v.h[1] = (_Float16)r1;
                v.h[2] = (_Float16)r2; v.h[3] = (_Float16)r3;
                *(uint2*)(hout + (size_t)m * K2 + n) = v.u;
                int p = __builtin_amdgcn_cvt_pk_fp8_f32(r0, r1, 0, false);
                p = __builtin_amdgcn_cvt_pk_fp8_f32(r2, r3, p, true);
                *(unsigned int*)(hout8 + (size_t)m * DIM + n) = (unsigned)p;
            }
        }
    }
}

// ---------------- graph mean-pool (fp16 h, sorted gids) ----------------
__global__ __launch_bounds__(256) void k_pool(const unsigned short* __restrict__ h,
                                              const int* __restrict__ gid,
                                              float* __restrict__ pooled) {
    int d = threadIdx.x & 127;
    int half = threadIdx.x >> 7;
    int n0 = blockIdx.x * 128;
    float acc = 0.f;
    int cur = -1;
    for (int i = half; i < 128; i += 2) {
        int n = n0 + i;
        if (n >= N_NODES) break;
        int g = gid[n];
        if (g != cur) {
            if (cur >= 0) atomicAdd(&pooled[(size_t)cur * DIM + d], acc);
            acc = 0.f;
            cur = g;
        }
        acc += h2f(h[(size_t)n * K2 + d]);
    }
    if (cur >= 0) atomicAdd(&pooled[(size_t)cur * DIM + d], acc);
}

// ---------------- classifier (fp32) ----------------
__global__ __launch_bounds__(256) void k_final(const float* __restrict__ pooled,
                                               const float* __restrict__ counts,
                                               const float* __restrict__ Wf,
                                               const float* __restrict__ bf,
                                               float* __restrict__ out) {
    int t = blockIdx.x * 256 + threadIdx.x;
    if (t >= N_GRAPHS * CLS) return;
    int g = t / CLS, c = t % CLS;
    float inv = 1.0f / fmaxf(counts[g], 1.0f);
    float s = 0.f;
    for (int k = 0; k < DIM; ++k) s += pooled[(size_t)g * DIM + k] * Wf[k * CLS + c];
    out[t] = s * inv + bf[c];
}

extern "C" void kernel_launch(void* const* d_in, const int* in_sizes, int n_in,
                              void* d_out, int out_size, void* d_ws, size_t ws_size,
                              hipStream_t stream) {
    const float* features = (const float*)d_in[0];
    const int*   esrc     = (const int*)d_in[1];
    const int*   edst     = (const int*)d_in[2];
    const int*   gids     = (const int*)d_in[3];
    const float* bs[3]  = {(const float*)d_in[6], (const float*)d_in[9], (const float*)d_in[12]};
    const float* Wf = (const float*)d_in[13];
    const float* bfv = (const float*)d_in[14];
    float* out = (float*)d_out;

    // ---- workspace layout ----
    int* deg_i  = (int*)d_ws;            // 50000 + gcount (zeroed as 50056 block)
    int* gcount = deg_i + 50000;         // 8
    int* rowptr = deg_i + 50056;         // 50064
    int* cursor = rowptr + 50064;        // 50048
    int* bsum   = cursor + 50048;        // 256
    int* eidx   = bsum + 256;            // 800000
    int2* stag  = (int2*)(eidx + 800000);        // 8*131072 int2 = 8 MB
    float* pooled = (float*)(stag + (size_t)NPART * PCAP);   // 16384
    float* counts = pooled + N_GRAPHS * DIM;     // 128
    unsigned short* C0 = (unsigned short*)(counts + 128);    // 50000*256 fp16
    unsigned short* C1 = C0 + (size_t)N_NODES * K2;
    unsigned short* C2 = C1 + (size_t)N_NODES * K2;
    unsigned short* Wt = C2 + (size_t)N_NODES * K2;          // 3*128*256 fp16
    unsigned char* F0 = (unsigned char*)(Wt + 3 * DIM * K2); // 50000*128 fp8 x3
    unsigned char* F1 = F0 + (size_t)N_NODES * DIM;
    unsigned char* F2 = F1 + (size_t)N_NODES * DIM;
    // total ~108 MB

    // init: casts + weight prep + zeroing + graph counts (one dispatch)
    k_init<<<(INIT_THREADS + 255) / 256, 256, 0, stream>>>(
        features, C0, F0,
        (const float*)d_in[4], (const float*)d_in[5],
        (const float*)d_in[7], (const float*)d_in[8],
        (const float*)d_in[10], (const float*)d_in[11],
        Wt, deg_i, pooled, gids, counts);

    // CSR build: bin(+deg) -> scan x2 -> fill
    k_bin<<<NBIN, 256, 0, stream>>>(esrc, edst, stag, gcount, deg_i);
    k_scan_part<<<NB_SCAN, 256, 0, stream>>>(deg_i, rowptr, bsum);
    k_scan_add<<<NB_SCAN, 256, 0, stream>>>(rowptr, bsum, cursor);
    k_fill2<<<NPART * 64, 256, 0, stream>>>(stag, gcount, cursor, eidx);

    unsigned short* C[4] = {C0, C1, C2, C0};
    unsigned char* F[4] = {F0, F1, F2, F0};
    for (int l = 0; l < 3; ++l) {
        k_gather<<<(N_NODES * 64 + 255) / 256, 256, 0, stream>>>(F[l], rowptr, eidx, C[l]);
        k_sage<<<(N_NODES + 127) / 128, 256, 0, stream>>>(
            C[l], Wt + (size_t)l * DIM * K2, bs[l], C[l + 1], F[l + 1]);
    }

    k_pool<<<(N_NODES + 127) / 128, 256, 0, stream>>>(C0, gids, pooled);
    k_final<<<(N_GRAPHS * CLS + 255) / 256, 256, 0, stream>>>(pooled, counts, Wf, bfv, out);
}